// Round 1
// baseline (3168.610 us; speedup 1.0000x reference)
//
#include <hip/hip_runtime.h>
#include <math.h>

#define DIM 256
#define D4  64        // DIM/4
#define BM  64
#define BN  64
#define BK  64
#define LDT 68        // padded LDS stride (floats): keeps b128 reads aligned, conflicts benign

// ---------------------------------------------------------------------------
// Kernel A: per-edge scatter of x rows into sbuf[dst] + degree count.
// 4 edges per 256-thread block iteration; one wave (64 lanes) per edge,
// each lane handles 4 contiguous floats (float4).
// ---------------------------------------------------------------------------
__global__ __launch_bounds__(256) void edge_scatter1(
    const float4* __restrict__ x4, const int* __restrict__ src,
    const int* __restrict__ dst, float* __restrict__ sbuf,
    float* __restrict__ cnt, int E) {
  const int lane = threadIdx.x & 63;
  const int sub  = threadIdx.x >> 6;
  const int ngrp = (E + 3) >> 2;
  for (int g = blockIdx.x; g < ngrp; g += gridDim.x) {
    const int e = (g << 2) + sub;
    if (e < E) {
      const int s = src[e];
      const int d = dst[e];
      const float4 v = x4[s * D4 + lane];
      float* p = sbuf + (size_t)d * DIM + lane * 4;
      unsafeAtomicAdd(p + 0, v.x);
      unsafeAtomicAdd(p + 1, v.y);
      unsafeAtomicAdd(p + 2, v.z);
      unsafeAtomicAdd(p + 3, v.w);
      if (lane == 0) unsafeAtomicAdd(cnt + d, 1.0f);
    }
  }
}

// ---------------------------------------------------------------------------
// Kernel B: inv_cnt = 1 / max(cnt, 1)
// ---------------------------------------------------------------------------
__global__ void inv_kernel(const float* __restrict__ cnt,
                           float* __restrict__ inv, int M) {
  int i = blockIdx.x * blockDim.x + threadIdx.x;
  if (i < M) inv[i] = 1.0f / fmaxf(cnt[i], 1.0f);
}

// ---------------------------------------------------------------------------
// Kernel C: fused dual GEMM + scale + bias + relu
//   H[i][j] = relu( (S[i,:] @ Wl[j,:]) * inv_cnt[i] + X[i,:] @ Wr[j,:] + b1[j] )
// NT layout (both operands contiguous along K). 64x64 tile, 4x4 micro-tile,
// A/B tiles stored K-major (transposed) in LDS so inner loop uses b128 reads.
// ---------------------------------------------------------------------------
__global__ __launch_bounds__(256) void gemm1_fused(
    const float* __restrict__ S, const float* __restrict__ X,
    const float* __restrict__ Wl, const float* __restrict__ Wr,
    const float* __restrict__ b1, const float* __restrict__ inv_cnt,
    float* __restrict__ H, int M) {
  __shared__ float As[BK][LDT];
  __shared__ float Axs[BK][LDT];
  __shared__ float Bls[BK][LDT];
  __shared__ float Brs[BK][LDT];

  const int tid  = threadIdx.x;
  const int row0 = blockIdx.x * BM;
  const int col0 = blockIdx.y * BN;

  const int lrow = tid >> 4;   // 0..15 loader row group
  const int kch  = tid & 15;   // float4 chunk along K

  const int tx = tid & 15, ty = tid >> 4;
  const int r0 = ty * 4, c0 = tx * 4;

  float accS[4][4] = {};
  float accX[4][4] = {};

  for (int kt = 0; kt < DIM; kt += BK) {
    #pragma unroll
    for (int rr = 0; rr < 4; ++rr) {
      const int row  = rr * 16 + lrow;
      const int grow = row0 + row;
      float4 vs = make_float4(0.f, 0.f, 0.f, 0.f), vx = vs;
      if (grow < M) {
        vs = *(const float4*)&S[(size_t)grow * DIM + kt + kch * 4];
        vx = *(const float4*)&X[(size_t)grow * DIM + kt + kch * 4];
      }
      const int wrow = col0 + row;  // always < 256
      const float4 vl = *(const float4*)&Wl[(size_t)wrow * DIM + kt + kch * 4];
      const float4 vr = *(const float4*)&Wr[(size_t)wrow * DIM + kt + kch * 4];
      const int kk = kch * 4;
      As[kk + 0][row] = vs.x; As[kk + 1][row] = vs.y;
      As[kk + 2][row] = vs.z; As[kk + 3][row] = vs.w;
      Axs[kk + 0][row] = vx.x; Axs[kk + 1][row] = vx.y;
      Axs[kk + 2][row] = vx.z; Axs[kk + 3][row] = vx.w;
      Bls[kk + 0][row] = vl.x; Bls[kk + 1][row] = vl.y;
      Bls[kk + 2][row] = vl.z; Bls[kk + 3][row] = vl.w;
      Brs[kk + 0][row] = vr.x; Brs[kk + 1][row] = vr.y;
      Brs[kk + 2][row] = vr.z; Brs[kk + 3][row] = vr.w;
    }
    __syncthreads();

    #pragma unroll 8
    for (int kk = 0; kk < BK; ++kk) {
      const float4 as4 = *(const float4*)&As[kk][r0];
      const float4 ax4 = *(const float4*)&Axs[kk][r0];
      const float4 bl4 = *(const float4*)&Bls[kk][c0];
      const float4 br4 = *(const float4*)&Brs[kk][c0];
      const float as_[4] = {as4.x, as4.y, as4.z, as4.w};
      const float ax_[4] = {ax4.x, ax4.y, ax4.z, ax4.w};
      const float bl_[4] = {bl4.x, bl4.y, bl4.z, bl4.w};
      const float br_[4] = {br4.x, br4.y, br4.z, br4.w};
      #pragma unroll
      for (int i = 0; i < 4; ++i)
        #pragma unroll
        for (int j = 0; j < 4; ++j) {
          accS[i][j] = fmaf(as_[i], bl_[j], accS[i][j]);
          accX[i][j] = fmaf(ax_[i], br_[j], accX[i][j]);
        }
    }
    __syncthreads();
  }

  #pragma unroll
  for (int i = 0; i < 4; ++i) {
    const int grow = row0 + r0 + i;
    if (grow < M) {
      const float inv = inv_cnt[grow];
      float4 o;
      o.x = fmaxf(accS[i][0] * inv + accX[i][0] + b1[col0 + c0 + 0], 0.f);
      o.y = fmaxf(accS[i][1] * inv + accX[i][1] + b1[col0 + c0 + 1], 0.f);
      o.z = fmaxf(accS[i][2] * inv + accX[i][2] + b1[col0 + c0 + 2], 0.f);
      o.w = fmaxf(accS[i][3] * inv + accX[i][3] + b1[col0 + c0 + 3], 0.f);
      *(float4*)&H[(size_t)grow * DIM + col0 + c0] = o;
    }
  }
}

// ---------------------------------------------------------------------------
// Kernel D: per-node projection to 4 scalars:
//   Y4[i] = { h_i@W2l[0], h_i@W2l[1], h_i@W2r[0], h_i@W2r[1] }
// One wave per node; lane holds 4 features; butterfly reduce.
// ---------------------------------------------------------------------------
__global__ __launch_bounds__(256) void proj2(
    const float4* __restrict__ H4, const float* __restrict__ W2l,
    const float* __restrict__ W2r, float4* __restrict__ Y4, int M) {
  const int lane = threadIdx.x & 63;
  const int wave = threadIdx.x >> 6;
  const int wavesTotal = (blockDim.x >> 6) * gridDim.x;
  const int gw = blockIdx.x * (blockDim.x >> 6) + wave;

  const float4 wl0 = *(const float4*)&W2l[0 * DIM + lane * 4];
  const float4 wl1 = *(const float4*)&W2l[1 * DIM + lane * 4];
  const float4 wr0 = *(const float4*)&W2r[0 * DIM + lane * 4];
  const float4 wr1 = *(const float4*)&W2r[1 * DIM + lane * 4];

  for (int i = gw; i < M; i += wavesTotal) {
    const float4 h = H4[(size_t)i * D4 + lane];
    float a0 = h.x * wl0.x + h.y * wl0.y + h.z * wl0.z + h.w * wl0.w;
    float a1 = h.x * wl1.x + h.y * wl1.y + h.z * wl1.z + h.w * wl1.w;
    float a2 = h.x * wr0.x + h.y * wr0.y + h.z * wr0.z + h.w * wr0.w;
    float a3 = h.x * wr1.x + h.y * wr1.y + h.z * wr1.z + h.w * wr1.w;
    #pragma unroll
    for (int off = 32; off; off >>= 1) {
      a0 += __shfl_xor(a0, off);
      a1 += __shfl_xor(a1, off);
      a2 += __shfl_xor(a2, off);
      a3 += __shfl_xor(a3, off);
    }
    if (lane == 0) Y4[i] = make_float4(a0, a1, a2, a3);
  }
}

// ---------------------------------------------------------------------------
// Kernel E: 2-dim scatter of projected lin_l values
// ---------------------------------------------------------------------------
__global__ __launch_bounds__(256) void edge_scatter2(
    const float4* __restrict__ Y4, const int* __restrict__ src,
    const int* __restrict__ dst, float* __restrict__ yagg, int E) {
  const int t = blockIdx.x * blockDim.x + threadIdx.x;
  const int stride = gridDim.x * blockDim.x;
  for (int e = t; e < E; e += stride) {
    const int s = src[e];
    const int d = dst[e];
    const float4 v = Y4[s];
    unsafeAtomicAdd(&yagg[2 * d + 0], v.x);
    unsafeAtomicAdd(&yagg[2 * d + 1], v.y);
  }
}

// ---------------------------------------------------------------------------
// Kernel F: out = log_softmax( yagg*inv + y_r + b2 ), 2 classes
// ---------------------------------------------------------------------------
__global__ void finalize(const float* __restrict__ yagg,
                         const float4* __restrict__ Y4,
                         const float* __restrict__ inv_cnt,
                         const float* __restrict__ b2,
                         float* __restrict__ out, int M) {
  int i = blockIdx.x * blockDim.x + threadIdx.x;
  if (i < M) {
    const float inv = inv_cnt[i];
    const float4 y = Y4[i];
    const float o0 = yagg[2 * i + 0] * inv + y.z + b2[0];
    const float o1 = yagg[2 * i + 1] * inv + y.w + b2[1];
    const float m = fmaxf(o0, o1);
    const float lse = m + logf(expf(o0 - m) + expf(o1 - m));
    out[2 * i + 0] = o0 - lse;
    out[2 * i + 1] = o1 - lse;
  }
}

extern "C" void kernel_launch(void* const* d_in, const int* in_sizes, int n_in,
                              void* d_out, int out_size, void* d_ws, size_t ws_size,
                              hipStream_t stream) {
  const float* x   = (const float*)d_in[0];
  const int*   ei  = (const int*)d_in[1];
  const float* W1l = (const float*)d_in[2];
  const float* b1  = (const float*)d_in[3];
  const float* W1r = (const float*)d_in[4];
  const float* W2l = (const float*)d_in[5];
  const float* b2  = (const float*)d_in[6];
  const float* W2r = (const float*)d_in[7];

  const int E = in_sizes[1] / 2;
  const int M = in_sizes[0] / DIM;   // 50000 nodes
  const int* src = ei;
  const int* dst = ei + E;

  float* ws = (float*)d_ws;
  size_t off = 0;
  float* sbuf = ws + off; off += (size_t)M * DIM;  // layer-1 segment sums
  float* cnt  = ws + off; off += M;                // degree counts
  float* yagg = ws + off; off += 2 * (size_t)M;    // layer-2 segment sums
  const size_t zbytes = off * sizeof(float);       // contiguous zero region
  float* H    = ws + off; off += (size_t)M * DIM;  // hidden activations
  float* Y4v  = ws + off; off += 4 * (size_t)M;    // {yl0,yl1,yr0,yr1} per node
  float* invc = ws + off; off += M;                // 1/max(deg,1)

  hipMemsetAsync(d_ws, 0, zbytes, stream);

  edge_scatter1<<<8192, 256, 0, stream>>>((const float4*)x, src, dst, sbuf, cnt, E);
  inv_kernel<<<(M + 255) / 256, 256, 0, stream>>>(cnt, invc, M);

  dim3 g1((M + BM - 1) / BM, DIM / BN);
  gemm1_fused<<<g1, 256, 0, stream>>>(sbuf, x, W1l, W1r, b1, invc, H, M);

  proj2<<<512, 256, 0, stream>>>((const float4*)H, W2l, W2r, (float4*)Y4v, M);
  edge_scatter2<<<2048, 256, 0, stream>>>((const float4*)Y4v, src, dst, yagg, E);
  finalize<<<(M + 255) / 256, 256, 0, stream>>>(yagg, (const float4*)Y4v, invc, b2,
                                               (float*)d_out, M);
}

// Round 2
// 681.532 us; speedup vs baseline: 4.6492x; 4.6492x over previous
//
#include <hip/hip_runtime.h>
#include <math.h>

#define DIM 256
#define D4  64        // DIM/4
#define BM  64
#define BN  64
#define BK  64
#define LDT 68        // padded LDS stride (floats)

// ---------------------------------------------------------------------------
// Sort pass 1: histogram of dst
// ---------------------------------------------------------------------------
__global__ __launch_bounds__(256) void hist_kernel(
    const int* __restrict__ dst, int* __restrict__ deg, int E) {
  int e = blockIdx.x * blockDim.x + threadIdx.x;
  if (e < E) atomicAdd(&deg[dst[e]], 1);
}

// ---------------------------------------------------------------------------
// Sort pass 2: single-block exclusive scan of deg -> rowptr, fill, invc
// ---------------------------------------------------------------------------
__global__ __launch_bounds__(1024) void scan_kernel(
    const int* __restrict__ deg, int* __restrict__ rowptr,
    int* __restrict__ fill, float* __restrict__ invc, int M) {
  __shared__ int part[1024];
  const int t = threadIdx.x;
  const int C = (M + 1023) / 1024;
  const int lo = t * C;
  const int hi = min(lo + C, M);
  int s = 0;
  for (int i = lo; i < hi; ++i) s += deg[i];
  part[t] = s;
  __syncthreads();
  for (int off = 1; off < 1024; off <<= 1) {
    int v = part[t];
    int u = (t >= off) ? part[t - off] : 0;
    __syncthreads();
    part[t] = v + u;
    __syncthreads();
  }
  int base = (t > 0) ? part[t - 1] : 0;
  for (int i = lo; i < hi; ++i) {
    const int d = deg[i];
    rowptr[i] = base;
    fill[i]   = base;
    invc[i]   = 1.0f / fmaxf((float)d, 1.0f);
    base += d;
  }
  if (t == 1023) rowptr[M] = part[1023];
}

// ---------------------------------------------------------------------------
// Sort pass 3: scatter src ids into CSR order
// ---------------------------------------------------------------------------
__global__ __launch_bounds__(256) void scatter_edges(
    const int* __restrict__ src, const int* __restrict__ dst,
    int* __restrict__ fill, int* __restrict__ esrc, int E) {
  int e = blockIdx.x * blockDim.x + threadIdx.x;
  if (e < E) {
    const int pos = atomicAdd(&fill[dst[e]], 1);
    esrc[pos] = src[e];
  }
}

// ---------------------------------------------------------------------------
// Gather-reduce: one wave per node, lane holds float4 (4 features).
// agg[i] = mean_{s in N(i)} x[s]   (mean folded in here)
// ---------------------------------------------------------------------------
__global__ __launch_bounds__(256) void gather1(
    const float4* __restrict__ x4, const int* __restrict__ esrc,
    const int* __restrict__ rowptr, const float* __restrict__ invc,
    float4* __restrict__ agg4, int M) {
  const int lane = threadIdx.x & 63;
  const int wave = threadIdx.x >> 6;
  const int i = blockIdx.x * 4 + wave;
  if (i >= M) return;
  const int k0 = rowptr[i];
  const int k1 = rowptr[i + 1];
  float4 a0 = make_float4(0.f, 0.f, 0.f, 0.f);
  float4 a1 = a0;
  int k = k0;
  for (; k + 1 < k1; k += 2) {
    const int s0 = esrc[k];
    const int s1 = esrc[k + 1];
    const float4 v0 = x4[(size_t)s0 * D4 + lane];
    const float4 v1 = x4[(size_t)s1 * D4 + lane];
    a0.x += v0.x; a0.y += v0.y; a0.z += v0.z; a0.w += v0.w;
    a1.x += v1.x; a1.y += v1.y; a1.z += v1.z; a1.w += v1.w;
  }
  if (k < k1) {
    const float4 v = x4[(size_t)esrc[k] * D4 + lane];
    a0.x += v.x; a0.y += v.y; a0.z += v.z; a0.w += v.w;
  }
  const float inv = invc[i];
  float4 o;
  o.x = (a0.x + a1.x) * inv;
  o.y = (a0.y + a1.y) * inv;
  o.z = (a0.z + a1.z) * inv;
  o.w = (a0.w + a1.w) * inv;
  agg4[(size_t)i * D4 + lane] = o;
}

// ---------------------------------------------------------------------------
// Fused dual GEMM + bias + relu (agg already holds the mean):
//   H[i][j] = relu( A[i,:]@Wl[j,:] + X[i,:]@Wr[j,:] + b1[j] )
// ---------------------------------------------------------------------------
__global__ __launch_bounds__(256) void gemm1_fused(
    const float* __restrict__ A, const float* __restrict__ X,
    const float* __restrict__ Wl, const float* __restrict__ Wr,
    const float* __restrict__ b1, float* __restrict__ H, int M) {
  __shared__ float As[BK][LDT];
  __shared__ float Axs[BK][LDT];
  __shared__ float Bls[BK][LDT];
  __shared__ float Brs[BK][LDT];

  const int tid  = threadIdx.x;
  const int row0 = blockIdx.x * BM;
  const int col0 = blockIdx.y * BN;

  const int lrow = tid >> 4;
  const int kch  = tid & 15;

  const int tx = tid & 15, ty = tid >> 4;
  const int r0 = ty * 4, c0 = tx * 4;

  float acc[4][4] = {};

  for (int kt = 0; kt < DIM; kt += BK) {
    #pragma unroll
    for (int rr = 0; rr < 4; ++rr) {
      const int row  = rr * 16 + lrow;
      const int grow = row0 + row;
      float4 vs = make_float4(0.f, 0.f, 0.f, 0.f), vx = vs;
      if (grow < M) {
        vs = *(const float4*)&A[(size_t)grow * DIM + kt + kch * 4];
        vx = *(const float4*)&X[(size_t)grow * DIM + kt + kch * 4];
      }
      const int wrow = col0 + row;
      const float4 vl = *(const float4*)&Wl[(size_t)wrow * DIM + kt + kch * 4];
      const float4 vr = *(const float4*)&Wr[(size_t)wrow * DIM + kt + kch * 4];
      const int kk = kch * 4;
      As[kk + 0][row] = vs.x; As[kk + 1][row] = vs.y;
      As[kk + 2][row] = vs.z; As[kk + 3][row] = vs.w;
      Axs[kk + 0][row] = vx.x; Axs[kk + 1][row] = vx.y;
      Axs[kk + 2][row] = vx.z; Axs[kk + 3][row] = vx.w;
      Bls[kk + 0][row] = vl.x; Bls[kk + 1][row] = vl.y;
      Bls[kk + 2][row] = vl.z; Bls[kk + 3][row] = vl.w;
      Brs[kk + 0][row] = vr.x; Brs[kk + 1][row] = vr.y;
      Brs[kk + 2][row] = vr.z; Brs[kk + 3][row] = vr.w;
    }
    __syncthreads();

    #pragma unroll 8
    for (int kk = 0; kk < BK; ++kk) {
      const float4 as4 = *(const float4*)&As[kk][r0];
      const float4 ax4 = *(const float4*)&Axs[kk][r0];
      const float4 bl4 = *(const float4*)&Bls[kk][c0];
      const float4 br4 = *(const float4*)&Brs[kk][c0];
      const float as_[4] = {as4.x, as4.y, as4.z, as4.w};
      const float ax_[4] = {ax4.x, ax4.y, ax4.z, ax4.w};
      const float bl_[4] = {bl4.x, bl4.y, bl4.z, bl4.w};
      const float br_[4] = {br4.x, br4.y, br4.z, br4.w};
      #pragma unroll
      for (int i = 0; i < 4; ++i)
        #pragma unroll
        for (int j = 0; j < 4; ++j) {
          acc[i][j] = fmaf(as_[i], bl_[j], acc[i][j]);
          acc[i][j] = fmaf(ax_[i], br_[j], acc[i][j]);
        }
    }
    __syncthreads();
  }

  #pragma unroll
  for (int i = 0; i < 4; ++i) {
    const int grow = row0 + r0 + i;
    if (grow < M) {
      float4 o;
      o.x = fmaxf(acc[i][0] + b1[col0 + c0 + 0], 0.f);
      o.y = fmaxf(acc[i][1] + b1[col0 + c0 + 1], 0.f);
      o.z = fmaxf(acc[i][2] + b1[col0 + c0 + 2], 0.f);
      o.w = fmaxf(acc[i][3] + b1[col0 + c0 + 3], 0.f);
      *(float4*)&H[(size_t)grow * DIM + col0 + c0] = o;
    }
  }
}

// ---------------------------------------------------------------------------
// Per-node projection: Y4[i] = { h@W2l[0], h@W2l[1], h@W2r[0], h@W2r[1] }
// ---------------------------------------------------------------------------
__global__ __launch_bounds__(256) void proj2(
    const float4* __restrict__ H4, const float* __restrict__ W2l,
    const float* __restrict__ W2r, float4* __restrict__ Y4, int M) {
  const int lane = threadIdx.x & 63;
  const int wave = threadIdx.x >> 6;
  const int wavesTotal = (blockDim.x >> 6) * gridDim.x;
  const int gw = blockIdx.x * (blockDim.x >> 6) + wave;

  const float4 wl0 = *(const float4*)&W2l[0 * DIM + lane * 4];
  const float4 wl1 = *(const float4*)&W2l[1 * DIM + lane * 4];
  const float4 wr0 = *(const float4*)&W2r[0 * DIM + lane * 4];
  const float4 wr1 = *(const float4*)&W2r[1 * DIM + lane * 4];

  for (int i = gw; i < M; i += wavesTotal) {
    const float4 h = H4[(size_t)i * D4 + lane];
    float a0 = h.x * wl0.x + h.y * wl0.y + h.z * wl0.z + h.w * wl0.w;
    float a1 = h.x * wl1.x + h.y * wl1.y + h.z * wl1.z + h.w * wl1.w;
    float a2 = h.x * wr0.x + h.y * wr0.y + h.z * wr0.z + h.w * wr0.w;
    float a3 = h.x * wr1.x + h.y * wr1.y + h.z * wr1.z + h.w * wr1.w;
    #pragma unroll
    for (int off = 32; off; off >>= 1) {
      a0 += __shfl_xor(a0, off);
      a1 += __shfl_xor(a1, off);
      a2 += __shfl_xor(a2, off);
      a3 += __shfl_xor(a3, off);
    }
    if (lane == 0) Y4[i] = make_float4(a0, a1, a2, a3);
  }
}

// ---------------------------------------------------------------------------
// Layer-2 aggregation + bias + log_softmax, one thread per node via CSR.
// ---------------------------------------------------------------------------
__global__ __launch_bounds__(256) void layer2_finalize(
    const float2* __restrict__ Y2,   // view of Y4: [2*i] = (yl0,yl1), [2*i+1] = (yr0,yr1)
    const int* __restrict__ esrc, const int* __restrict__ rowptr,
    const float* __restrict__ invc, const float* __restrict__ b2,
    float* __restrict__ out, int M) {
  int i = blockIdx.x * blockDim.x + threadIdx.x;
  if (i < M) {
    const int k0 = rowptr[i];
    const int k1 = rowptr[i + 1];
    float a0 = 0.f, a1 = 0.f;
    for (int k = k0; k < k1; ++k) {
      const float2 y = Y2[2 * (size_t)esrc[k]];
      a0 += y.x; a1 += y.y;
    }
    const float inv = invc[i];
    const float2 yr = Y2[2 * (size_t)i + 1];
    const float o0 = a0 * inv + yr.x + b2[0];
    const float o1 = a1 * inv + yr.y + b2[1];
    const float m = fmaxf(o0, o1);
    const float lse = m + logf(expf(o0 - m) + expf(o1 - m));
    out[2 * i + 0] = o0 - lse;
    out[2 * i + 1] = o1 - lse;
  }
}

extern "C" void kernel_launch(void* const* d_in, const int* in_sizes, int n_in,
                              void* d_out, int out_size, void* d_ws, size_t ws_size,
                              hipStream_t stream) {
  const float* x   = (const float*)d_in[0];
  const int*   ei  = (const int*)d_in[1];
  const float* W1l = (const float*)d_in[2];
  const float* b1  = (const float*)d_in[3];
  const float* W1r = (const float*)d_in[4];
  const float* W2l = (const float*)d_in[5];
  const float* b2  = (const float*)d_in[6];
  const float* W2r = (const float*)d_in[7];

  const int E = in_sizes[1] / 2;
  const int M = in_sizes[0] / DIM;   // 50000
  const int* src = ei;
  const int* dst = ei + E;

  char* ws = (char*)d_ws;
  size_t off = 0;
  float* agg  = (float*)(ws + off); off += (size_t)M * DIM * 4;   // mean-aggregated x
  float* H    = (float*)(ws + off); off += (size_t)M * DIM * 4;   // hidden activations
  float* Y4v  = (float*)(ws + off); off += (size_t)M * 4 * 4;     // per-node projections
  float* invc = (float*)(ws + off); off += (size_t)M * 4;         // 1/max(deg,1)
  int* deg    = (int*)(ws + off);   off += (size_t)M * 4;         // degree histogram (zeroed)
  int* fill   = (int*)(ws + off);   off += (size_t)M * 4;         // CSR fill cursors
  int* rowptr = (int*)(ws + off);   off += (size_t)(M + 1) * 4;   // CSR row pointers
  int* esrc   = (int*)(ws + off);   off += (size_t)E * 4;         // CSR-ordered src ids

  hipMemsetAsync(deg, 0, (size_t)M * 4, stream);

  const int EB = (E + 255) / 256;
  hist_kernel<<<EB, 256, 0, stream>>>(dst, deg, E);
  scan_kernel<<<1, 1024, 0, stream>>>(deg, rowptr, fill, invc, M);
  scatter_edges<<<EB, 256, 0, stream>>>(src, dst, fill, esrc, E);
  gather1<<<(M + 3) / 4, 256, 0, stream>>>((const float4*)x, esrc, rowptr, invc,
                                           (float4*)agg, M);

  dim3 g1((M + BM - 1) / BM, DIM / BN);
  gemm1_fused<<<g1, 256, 0, stream>>>(agg, x, W1l, W1r, b1, H, M);

  proj2<<<512, 256, 0, stream>>>((const float4*)H, W2l, W2r, (float4*)Y4v, M);
  layer2_finalize<<<(M + 255) / 256, 256, 0, stream>>>(
      (const float2*)Y4v, esrc, rowptr, invc, b2, (float*)d_out, M);
}

// Round 4
// 452.683 us; speedup vs baseline: 6.9996x; 1.5055x over previous
//
#include <hip/hip_runtime.h>
#include <math.h>

#define DIM 256
#define GBM 128
#define GBN 128
#define GBK 64
#define LDS_K 72   // padded LDS row stride (bf16 elems): 144B = 36 dwords ≡ 4 (mod 32 banks)

typedef short bf16x8 __attribute__((ext_vector_type(8)));
typedef float f32x4 __attribute__((ext_vector_type(4)));

// fp32 -> bf16 (RNE) as raw ushort
__device__ __forceinline__ ushort f2bf(float f) {
  uint u = __float_as_uint(f);
  u += 0x7fffu + ((u >> 16) & 1u);
  return (ushort)(u >> 16);
}
// bf16 bits -> fp32
__device__ __forceinline__ float bf2f(uint bits) {
  return __uint_as_float(bits << 16);
}

// ---------------------------------------------------------------------------
// x (fp32) -> xb (bf16)
// ---------------------------------------------------------------------------
__global__ __launch_bounds__(256) void convert_x(
    const float4* __restrict__ x4, ushort* __restrict__ xb, int n4) {
  int i = blockIdx.x * blockDim.x + threadIdx.x;
  const int stride = gridDim.x * blockDim.x;
  for (; i < n4; i += stride) {
    const float4 v = x4[i];
    ushort4 o;
    o.x = f2bf(v.x); o.y = f2bf(v.y); o.z = f2bf(v.z); o.w = f2bf(v.w);
    *(ushort4*)&xb[i * 4] = o;
  }
}

// ---------------------------------------------------------------------------
// Wb[n][k] = bf16( k<256 ? W1l[n][k] : W1r[n][k-256] ),  [256][512]
// ---------------------------------------------------------------------------
__global__ __launch_bounds__(256) void wcat_kernel(
    const float* __restrict__ Wl, const float* __restrict__ Wr,
    ushort* __restrict__ Wb) {
  const int idx = blockIdx.x * 256 + threadIdx.x;  // 0..131071
  const int n = idx >> 9, k = idx & 511;
  const float v = (k < 256) ? Wl[n * 256 + k] : Wr[n * 256 + (k - 256)];
  Wb[idx] = f2bf(v);
}

// ---------------------------------------------------------------------------
// Sort pass 1: histogram of dst
// ---------------------------------------------------------------------------
__global__ __launch_bounds__(256) void hist_kernel(
    const int* __restrict__ dst, int* __restrict__ deg, int E) {
  int e = blockIdx.x * blockDim.x + threadIdx.x;
  if (e < E) atomicAdd(&deg[dst[e]], 1);
}

// ---------------------------------------------------------------------------
// Sort pass 2: single-block exclusive scan -> rowptr, fill, invc
// ---------------------------------------------------------------------------
__global__ __launch_bounds__(1024) void scan_kernel(
    const int* __restrict__ deg, int* __restrict__ rowptr,
    int* __restrict__ fill, float* __restrict__ invc, int M) {
  __shared__ int part[1024];
  const int t = threadIdx.x;
  const int C = (M + 1023) / 1024;
  const int lo = t * C;
  const int hi = min(lo + C, M);
  int s = 0;
  for (int i = lo; i < hi; ++i) s += deg[i];
  part[t] = s;
  __syncthreads();
  for (int off = 1; off < 1024; off <<= 1) {
    int v = part[t];
    int u = (t >= off) ? part[t - off] : 0;
    __syncthreads();
    part[t] = v + u;
    __syncthreads();
  }
  int base = (t > 0) ? part[t - 1] : 0;
  for (int i = lo; i < hi; ++i) {
    const int d = deg[i];
    rowptr[i] = base;
    fill[i]   = base;
    invc[i]   = 1.0f / fmaxf((float)d, 1.0f);
    base += d;
  }
  if (t == 1023) rowptr[M] = part[1023];
}

// ---------------------------------------------------------------------------
// Sort pass 3: scatter src ids into CSR order
// ---------------------------------------------------------------------------
__global__ __launch_bounds__(256) void scatter_edges(
    const int* __restrict__ src, const int* __restrict__ dst,
    int* __restrict__ fill, int* __restrict__ esrc, int E) {
  int e = blockIdx.x * blockDim.x + threadIdx.x;
  if (e < E) {
    const int pos = atomicAdd(&fill[dst[e]], 1);
    esrc[pos] = src[e];
  }
}

// ---------------------------------------------------------------------------
// Gather-reduce (bf16 in, bf16 out): one wave per node, lane holds 4 feats.
// aggb[i] = bf16( mean_{s in N(i)} xb[s] )
// ---------------------------------------------------------------------------
__global__ __launch_bounds__(256) void gather1(
    const ushort* __restrict__ xb, const int* __restrict__ esrc,
    const int* __restrict__ rowptr, const float* __restrict__ invc,
    ushort* __restrict__ aggb, int M) {
  const int lane = threadIdx.x & 63;
  const int wave = threadIdx.x >> 6;
  const int i = blockIdx.x * 4 + wave;
  if (i >= M) return;
  const int k0 = rowptr[i];
  const int k1 = rowptr[i + 1];
  float a0 = 0.f, a1 = 0.f, a2 = 0.f, a3 = 0.f;
  float b0 = 0.f, b1_ = 0.f, b2_ = 0.f, b3 = 0.f;
  int k = k0;
  for (; k + 1 < k1; k += 2) {
    const int s0 = esrc[k];
    const int s1 = esrc[k + 1];
    const uint2 v0 = *(const uint2*)(xb + (size_t)s0 * DIM + lane * 4);
    const uint2 v1 = *(const uint2*)(xb + (size_t)s1 * DIM + lane * 4);
    a0 += bf2f(v0.x & 0xffffu); a1 += bf2f(v0.x >> 16);
    a2 += bf2f(v0.y & 0xffffu); a3 += bf2f(v0.y >> 16);
    b0 += bf2f(v1.x & 0xffffu); b1_ += bf2f(v1.x >> 16);
    b2_ += bf2f(v1.y & 0xffffu); b3 += bf2f(v1.y >> 16);
  }
  if (k < k1) {
    const uint2 v = *(const uint2*)(xb + (size_t)esrc[k] * DIM + lane * 4);
    a0 += bf2f(v.x & 0xffffu); a1 += bf2f(v.x >> 16);
    a2 += bf2f(v.y & 0xffffu); a3 += bf2f(v.y >> 16);
  }
  const float inv = invc[i];
  ushort4 o;
  o.x = f2bf((a0 + b0) * inv);
  o.y = f2bf((a1 + b1_) * inv);
  o.z = f2bf((a2 + b2_) * inv);
  o.w = f2bf((a3 + b3) * inv);
  *(ushort4*)&aggb[(size_t)i * DIM + lane * 4] = o;
}

// ---------------------------------------------------------------------------
// MFMA GEMM: H = relu([agg | x] @ [Wl | Wr]^T + b1), all bf16, fp32 accum.
// 128x128 tile, BK=64, 4 waves x (64x64), mfma_f32_16x16x32_bf16.
// ---------------------------------------------------------------------------
__global__ __launch_bounds__(256) void gemm1_mfma(
    const ushort* __restrict__ Ab, const ushort* __restrict__ Xb,
    const ushort* __restrict__ Wb, const float* __restrict__ b1,
    ushort* __restrict__ Hb, int M) {
  __shared__ __align__(16) ushort As[GBM * LDS_K];
  __shared__ __align__(16) ushort Bs[GBN * LDS_K];

  const int tid  = threadIdx.x;
  const int lane = tid & 63;
  const int wave = tid >> 6;
  const int wm = wave >> 1, wn = wave & 1;
  const int row0 = blockIdx.x * GBM;
  const int col0 = blockIdx.y * GBN;

  const int lr = tid >> 3;  // loader base row 0..31
  const int lc = tid & 7;   // loader chunk (8 bf16)

  const int frow = lane & 15;        // fragment row (A) / col (B)
  const int fk   = (lane >> 4) * 8;  // fragment k base within 32

  f32x4 acc[4][4] = {};

  for (int kt = 0; kt < 512; kt += GBK) {
    const ushort* srcA = (kt < 256) ? Ab : Xb;
    const int kofs = kt & 255;
    #pragma unroll
    for (int i = 0; i < 4; ++i) {
      const int r = lr + i * 32;
      const int grow = row0 + r;
      uint4 v = make_uint4(0, 0, 0, 0);
      if (grow < M) v = *(const uint4*)(srcA + (size_t)grow * DIM + kofs + lc * 8);
      *(uint4*)&As[r * LDS_K + lc * 8] = v;
    }
    #pragma unroll
    for (int i = 0; i < 4; ++i) {
      const int r = lr + i * 32;
      const uint4 v = *(const uint4*)(Wb + (size_t)(col0 + r) * 512 + kt + lc * 8);
      *(uint4*)&Bs[r * LDS_K + lc * 8] = v;
    }
    __syncthreads();

    #pragma unroll
    for (int s = 0; s < 2; ++s) {
      bf16x8 a[4], b[4];
      #pragma unroll
      for (int i = 0; i < 4; ++i)
        a[i] = *(const bf16x8*)&As[(wm * 64 + i * 16 + frow) * LDS_K + s * 32 + fk];
      #pragma unroll
      for (int j = 0; j < 4; ++j)
        b[j] = *(const bf16x8*)&Bs[(wn * 64 + j * 16 + frow) * LDS_K + s * 32 + fk];
      #pragma unroll
      for (int i = 0; i < 4; ++i)
        #pragma unroll
        for (int j = 0; j < 4; ++j)
          acc[i][j] = __builtin_amdgcn_mfma_f32_16x16x32_bf16(a[i], b[j], acc[i][j], 0, 0, 0);
    }
    __syncthreads();
  }

  // epilogue: C/D layout col = lane&15, row = (lane>>4)*4 + reg
  #pragma unroll
  for (int i = 0; i < 4; ++i) {
    #pragma unroll
    for (int j = 0; j < 4; ++j) {
      const int col = col0 + wn * 64 + j * 16 + (lane & 15);
      const float bias = b1[col];
      #pragma unroll
      for (int r = 0; r < 4; ++r) {
        const int grow = row0 + wm * 64 + i * 16 + (lane >> 4) * 4 + r;
        if (grow < M) {
          const float v = fmaxf(acc[i][j][r] + bias, 0.f);
          Hb[(size_t)grow * DIM + col] = f2bf(v);
        }
      }
    }
  }
}

// ---------------------------------------------------------------------------
// Per-node projection (bf16 H): Y4[i] = { h@W2l[0], h@W2l[1], h@W2r[0], h@W2r[1] }
// ---------------------------------------------------------------------------
__global__ __launch_bounds__(256) void proj2(
    const ushort* __restrict__ Hb, const float* __restrict__ W2l,
    const float* __restrict__ W2r, float4* __restrict__ Y4, int M) {
  const int lane = threadIdx.x & 63;
  const int wave = threadIdx.x >> 6;
  const int wavesTotal = (blockDim.x >> 6) * gridDim.x;
  const int gw = blockIdx.x * (blockDim.x >> 6) + wave;

  const float4 wl0 = *(const float4*)&W2l[0 * DIM + lane * 4];
  const float4 wl1 = *(const float4*)&W2l[1 * DIM + lane * 4];
  const float4 wr0 = *(const float4*)&W2r[0 * DIM + lane * 4];
  const float4 wr1 = *(const float4*)&W2r[1 * DIM + lane * 4];

  for (int i = gw; i < M; i += wavesTotal) {
    const uint2 hv = *(const uint2*)(Hb + (size_t)i * DIM + lane * 4);
    const float h0 = bf2f(hv.x & 0xffffu), h1 = bf2f(hv.x >> 16);
    const float h2 = bf2f(hv.y & 0xffffu), h3 = bf2f(hv.y >> 16);
    float a0 = h0 * wl0.x + h1 * wl0.y + h2 * wl0.z + h3 * wl0.w;
    float a1 = h0 * wl1.x + h1 * wl1.y + h2 * wl1.z + h3 * wl1.w;
    float a2 = h0 * wr0.x + h1 * wr0.y + h2 * wr0.z + h3 * wr0.w;
    float a3 = h0 * wr1.x + h1 * wr1.y + h2 * wr1.z + h3 * wr1.w;
    #pragma unroll
    for (int off = 32; off; off >>= 1) {
      a0 += __shfl_xor(a0, off);
      a1 += __shfl_xor(a1, off);
      a2 += __shfl_xor(a2, off);
      a3 += __shfl_xor(a3, off);
    }
    if (lane == 0) Y4[i] = make_float4(a0, a1, a2, a3);
  }
}

// ---------------------------------------------------------------------------
// Layer-2 aggregation + bias + log_softmax, one thread per node via CSR.
// ---------------------------------------------------------------------------
__global__ __launch_bounds__(256) void layer2_finalize(
    const float2* __restrict__ Y2, const int* __restrict__ esrc,
    const int* __restrict__ rowptr, const float* __restrict__ invc,
    const float* __restrict__ b2, float* __restrict__ out, int M) {
  int i = blockIdx.x * blockDim.x + threadIdx.x;
  if (i < M) {
    const int k0 = rowptr[i];
    const int k1 = rowptr[i + 1];
    float a0 = 0.f, a1 = 0.f;
    for (int k = k0; k < k1; ++k) {
      const float2 y = Y2[2 * (size_t)esrc[k]];
      a0 += y.x; a1 += y.y;
    }
    const float inv = invc[i];
    const float2 yr = Y2[2 * (size_t)i + 1];
    const float o0 = a0 * inv + yr.x + b2[0];
    const float o1 = a1 * inv + yr.y + b2[1];
    const float m = fmaxf(o0, o1);
    const float lse = m + logf(expf(o0 - m) + expf(o1 - m));
    out[2 * i + 0] = o0 - lse;
    out[2 * i + 1] = o1 - lse;
  }
}

extern "C" void kernel_launch(void* const* d_in, const int* in_sizes, int n_in,
                              void* d_out, int out_size, void* d_ws, size_t ws_size,
                              hipStream_t stream) {
  const float* x   = (const float*)d_in[0];
  const int*   ei  = (const int*)d_in[1];
  const float* W1l = (const float*)d_in[2];
  const float* b1  = (const float*)d_in[3];
  const float* W1r = (const float*)d_in[4];
  const float* W2l = (const float*)d_in[5];
  const float* b2  = (const float*)d_in[6];
  const float* W2r = (const float*)d_in[7];

  const int E = in_sizes[1] / 2;
  const int M = in_sizes[0] / DIM;  // 50000
  const int* src = ei;
  const int* dst = ei + E;

  char* ws = (char*)d_ws;
  size_t off = 0;
  ushort* xb   = (ushort*)(ws + off); off += (size_t)M * DIM * 2;      // x in bf16
  ushort* aggb = (ushort*)(ws + off); off += (size_t)M * DIM * 2;      // mean-agg in bf16
  ushort* Hb   = (ushort*)(ws + off); off += (size_t)M * DIM * 2;      // hidden bf16
  ushort* Wb   = (ushort*)(ws + off); off += (size_t)256 * 512 * 2;    // [Wl|Wr] bf16
  float* Y4v   = (float*)(ws + off);  off += (size_t)M * 4 * 4;        // projections
  float* invc  = (float*)(ws + off);  off += (size_t)M * 4;
  int* deg     = (int*)(ws + off);    off += (size_t)M * 4;
  int* fill    = (int*)(ws + off);    off += (size_t)M * 4;
  int* rowptr  = (int*)(ws + off);    off += (size_t)(M + 1) * 4;
  int* esrc    = (int*)(ws + off);    off += (size_t)E * 4;

  hipMemsetAsync(deg, 0, (size_t)M * 4, stream);

  const int EB = (E + 255) / 256;
  convert_x<<<1024, 256, 0, stream>>>((const float4*)x, xb, M * DIM / 4);
  wcat_kernel<<<512, 256, 0, stream>>>(W1l, W1r, Wb);
  hist_kernel<<<EB, 256, 0, stream>>>(dst, deg, E);
  scan_kernel<<<1, 1024, 0, stream>>>(deg, rowptr, fill, invc, M);
  scatter_edges<<<EB, 256, 0, stream>>>(src, dst, fill, esrc, E);
  gather1<<<(M + 3) / 4, 256, 0, stream>>>(xb, esrc, rowptr, invc, aggb, M);

  dim3 g1((M + GBM - 1) / GBM, DIM / GBN);
  gemm1_mfma<<<g1, 256, 0, stream>>>(aggb, xb, Wb, b1, Hb, M);

  proj2<<<512, 256, 0, stream>>>(Hb, W2l, W2r, (float4*)Y4v, M);
  layer2_finalize<<<(M + 255) / 256, 256, 0, stream>>>(
      (const float2*)Y4v, esrc, rowptr, invc, b2, (float*)d_out, M);
}

// Round 5
// 315.258 us; speedup vs baseline: 10.0508x; 1.4359x over previous
//
#include <hip/hip_runtime.h>
#include <math.h>

#define DIM 256
#define GBM 128
#define GBN 128
#define GBK 64
#define LDS_K 72     // padded LDS row stride (bf16): 144B ≡ 4 dwords (mod 32 banks)
#define SCHUNK 1024  // elements per scan block

typedef short bf16x8 __attribute__((ext_vector_type(8)));
typedef float f32x4 __attribute__((ext_vector_type(4)));

// fp32 -> bf16 (RNE) raw bits
__device__ __forceinline__ ushort f2bf(float f) {
  uint u = __float_as_uint(f);
  u += 0x7fffu + ((u >> 16) & 1u);
  return (ushort)(u >> 16);
}
__device__ __forceinline__ float bf2f(uint bits) {
  return __uint_as_float(bits << 16);
}

// ---------------------------------------------------------------------------
// x (fp32) -> xb (bf16)
// ---------------------------------------------------------------------------
__global__ __launch_bounds__(256) void convert_x(
    const float4* __restrict__ x4, ushort* __restrict__ xb, int n4) {
  int i = blockIdx.x * blockDim.x + threadIdx.x;
  const int stride = gridDim.x * blockDim.x;
  for (; i < n4; i += stride) {
    const float4 v = x4[i];
    ushort4 o;
    o.x = f2bf(v.x); o.y = f2bf(v.y); o.z = f2bf(v.z); o.w = f2bf(v.w);
    *(ushort4*)&xb[i * 4] = o;
  }
}

// ---------------------------------------------------------------------------
// Weight prep: Wb[256][512] = bf16([W1l | W1r]); W2b[16][256] = bf16 rows
// {W2l[0], W2l[1], W2r[0], W2r[1], 0...} (zero-padded to 16 for MFMA B-frag).
// ---------------------------------------------------------------------------
__global__ __launch_bounds__(256) void wcat_kernel(
    const float* __restrict__ Wl, const float* __restrict__ Wr,
    const float* __restrict__ W2l, const float* __restrict__ W2r,
    ushort* __restrict__ Wb, ushort* __restrict__ W2b) {
  const int idx = blockIdx.x * 256 + threadIdx.x;  // 0..135167
  if (idx < 131072) {
    const int n = idx >> 9, k = idx & 511;
    const float v = (k < 256) ? Wl[n * 256 + k] : Wr[n * 256 + (k - 256)];
    Wb[idx] = f2bf(v);
  } else {
    const int w2 = idx - 131072;           // 0..4095
    const int row = w2 >> 8, k = w2 & 255; // row 0..15
    float v = 0.f;
    if (row < 2)      v = W2l[row * 256 + k];
    else if (row < 4) v = W2r[(row - 2) * 256 + k];
    W2b[w2] = f2bf(v);
  }
}

// ---------------------------------------------------------------------------
// Sort pass 1: histogram of dst
// ---------------------------------------------------------------------------
__global__ __launch_bounds__(256) void hist_kernel(
    const int* __restrict__ dst, int* __restrict__ deg, int E) {
  int e = blockIdx.x * blockDim.x + threadIdx.x;
  if (e < E) atomicAdd(&deg[dst[e]], 1);
}

// ---------------------------------------------------------------------------
// Scan phase A: per-block (1024-elem chunk) totals
// ---------------------------------------------------------------------------
__global__ __launch_bounds__(256) void scan_partial(
    const int* __restrict__ deg, int* __restrict__ bsum, int M) {
  const int base = blockIdx.x * SCHUNK + threadIdx.x * 4;
  int s = 0;
  if (base + 3 < M) {
    const int4 v = *(const int4*)(deg + base);
    s = v.x + v.y + v.z + v.w;
  } else {
    for (int j = 0; j < 4; ++j) if (base + j < M) s += deg[base + j];
  }
  #pragma unroll
  for (int off = 32; off; off >>= 1) s += __shfl_xor(s, off);
  __shared__ int ws[4];
  if ((threadIdx.x & 63) == 0) ws[threadIdx.x >> 6] = s;
  __syncthreads();
  if (threadIdx.x == 0) bsum[blockIdx.x] = ws[0] + ws[1] + ws[2] + ws[3];
}

// ---------------------------------------------------------------------------
// Scan phase B: exclusive scan of block sums (nb <= 1024), one block
// ---------------------------------------------------------------------------
__global__ __launch_bounds__(1024) void scan_sums(
    int* __restrict__ bsum, int nb) {
  __shared__ int sh[1024];
  const int t = threadIdx.x;
  const int orig = (t < nb) ? bsum[t] : 0;
  sh[t] = orig;
  __syncthreads();
  for (int off = 1; off < 1024; off <<= 1) {
    const int v = sh[t];
    const int u = (t >= off) ? sh[t - off] : 0;
    __syncthreads();
    sh[t] = v + u;
    __syncthreads();
  }
  if (t < nb) bsum[t] = sh[t] - orig;  // exclusive
}

// ---------------------------------------------------------------------------
// Scan phase C: intra-block scan + block offset -> rowptr, fill, invc
// ---------------------------------------------------------------------------
__global__ __launch_bounds__(256) void scan_finalize(
    const int* __restrict__ deg, const int* __restrict__ bsum,
    int* __restrict__ rowptr, int* __restrict__ fill,
    float* __restrict__ invc, int M) {
  const int t = threadIdx.x;
  const int lane = t & 63;
  const int wid = t >> 6;
  const int base = blockIdx.x * SCHUNK + t * 4;
  int d[4];
  #pragma unroll
  for (int j = 0; j < 4; ++j) d[j] = (base + j < M) ? deg[base + j] : 0;
  const int tsum = d[0] + d[1] + d[2] + d[3];
  int v = tsum;  // inclusive wave scan
  #pragma unroll
  for (int off = 1; off < 64; off <<= 1) {
    const int u = __shfl_up(v, off);
    if (lane >= off) v += u;
  }
  __shared__ int wtot[4];
  if (lane == 63) wtot[wid] = v;
  __syncthreads();
  int wbase = 0;
  for (int w = 0; w < wid; ++w) wbase += wtot[w];
  int run = bsum[blockIdx.x] + wbase + v - tsum;  // exclusive prefix
  #pragma unroll
  for (int j = 0; j < 4; ++j) {
    const int idx = base + j;
    if (idx < M) {
      rowptr[idx] = run;
      fill[idx]   = run;
      invc[idx]   = 1.0f / fmaxf((float)d[j], 1.0f);
      run += d[j];
      if (idx == M - 1) rowptr[M] = run;
    }
  }
}

// ---------------------------------------------------------------------------
// Sort pass 3: scatter src ids into CSR order
// ---------------------------------------------------------------------------
__global__ __launch_bounds__(256) void scatter_edges(
    const int* __restrict__ src, const int* __restrict__ dst,
    int* __restrict__ fill, int* __restrict__ esrc, int E) {
  int e = blockIdx.x * blockDim.x + threadIdx.x;
  if (e < E) {
    const int pos = atomicAdd(&fill[dst[e]], 1);
    esrc[pos] = src[e];
  }
}

// ---------------------------------------------------------------------------
// Gather-reduce v2: one wave per node; half-wave split (lanes 0-31 even edge,
// 32-63 odd edge), each lane loads uint4 = 8 bf16 feats; 4 edges in flight.
// ---------------------------------------------------------------------------
__global__ __launch_bounds__(256) void gather1(
    const ushort* __restrict__ xb, const int* __restrict__ esrc,
    const int* __restrict__ rowptr, const float* __restrict__ invc,
    ushort* __restrict__ aggb, int M) {
  const int lane = threadIdx.x & 63;
  const int wave = threadIdx.x >> 6;
  const int half = lane >> 5;
  const int fl   = lane & 31;   // 16B chunk (8 feats)
  const int i = blockIdx.x * 4 + wave;
  if (i >= M) return;
  const int k0 = rowptr[i];
  const int k1 = rowptr[i + 1];
  float s0 = 0.f, s1 = 0.f, s2 = 0.f, s3 = 0.f;
  float s4 = 0.f, s5 = 0.f, s6 = 0.f, s7 = 0.f;

#define ACC(v)                                                  \
  do {                                                          \
    s0 += bf2f((v).x & 0xffffu); s1 += bf2f((v).x >> 16);       \
    s2 += bf2f((v).y & 0xffffu); s3 += bf2f((v).y >> 16);       \
    s4 += bf2f((v).z & 0xffffu); s5 += bf2f((v).z >> 16);       \
    s6 += bf2f((v).w & 0xffffu); s7 += bf2f((v).w >> 16);       \
  } while (0)

  int k = k0;
  for (; k + 3 < k1; k += 4) {
    const int e0 = esrc[k + half];
    const int e1 = esrc[k + 2 + half];
    const uint4 v0 = *(const uint4*)(xb + (size_t)e0 * DIM + fl * 8);
    const uint4 v1 = *(const uint4*)(xb + (size_t)e1 * DIM + fl * 8);
    ACC(v0);
    ACC(v1);
  }
  for (; k + 1 < k1; k += 2) {
    const int e = esrc[k + half];
    const uint4 v = *(const uint4*)(xb + (size_t)e * DIM + fl * 8);
    ACC(v);
  }
  if (k < k1 && half == 0) {
    const uint4 v = *(const uint4*)(xb + (size_t)esrc[k] * DIM + fl * 8);
    ACC(v);
  }
#undef ACC

  s0 += __shfl_xor(s0, 32); s1 += __shfl_xor(s1, 32);
  s2 += __shfl_xor(s2, 32); s3 += __shfl_xor(s3, 32);
  s4 += __shfl_xor(s4, 32); s5 += __shfl_xor(s5, 32);
  s6 += __shfl_xor(s6, 32); s7 += __shfl_xor(s7, 32);

  if (half == 0) {
    const float inv = invc[i];
    uint4 o;
    o.x = (uint)f2bf(s0 * inv) | ((uint)f2bf(s1 * inv) << 16);
    o.y = (uint)f2bf(s2 * inv) | ((uint)f2bf(s3 * inv) << 16);
    o.z = (uint)f2bf(s4 * inv) | ((uint)f2bf(s5 * inv) << 16);
    o.w = (uint)f2bf(s6 * inv) | ((uint)f2bf(s7 * inv) << 16);
    *(uint4*)(aggb + (size_t)i * DIM + fl * 8) = o;
  }
}

// ---------------------------------------------------------------------------
// MFMA GEMM: H = relu([agg | x] @ [Wl | Wr]^T + b1), bf16 in, fp32 accum.
// ---------------------------------------------------------------------------
__global__ __launch_bounds__(256) void gemm1_mfma(
    const ushort* __restrict__ Ab, const ushort* __restrict__ Xb,
    const ushort* __restrict__ Wb, const float* __restrict__ b1,
    ushort* __restrict__ Hb, int M) {
  __shared__ __align__(16) ushort As[GBM * LDS_K];
  __shared__ __align__(16) ushort Bs[GBN * LDS_K];

  const int tid  = threadIdx.x;
  const int lane = tid & 63;
  const int wave = tid >> 6;
  const int wm = wave >> 1, wn = wave & 1;
  const int row0 = blockIdx.x * GBM;
  const int col0 = blockIdx.y * GBN;

  const int lr = tid >> 3;
  const int lc = tid & 7;

  const int frow = lane & 15;
  const int fk   = (lane >> 4) * 8;

  f32x4 acc[4][4] = {};

  for (int kt = 0; kt < 512; kt += GBK) {
    const ushort* srcA = (kt < 256) ? Ab : Xb;
    const int kofs = kt & 255;
    #pragma unroll
    for (int i = 0; i < 4; ++i) {
      const int r = lr + i * 32;
      const int grow = row0 + r;
      uint4 v = make_uint4(0, 0, 0, 0);
      if (grow < M) v = *(const uint4*)(srcA + (size_t)grow * DIM + kofs + lc * 8);
      *(uint4*)&As[r * LDS_K + lc * 8] = v;
    }
    #pragma unroll
    for (int i = 0; i < 4; ++i) {
      const int r = lr + i * 32;
      const uint4 v = *(const uint4*)(Wb + (size_t)(col0 + r) * 512 + kt + lc * 8);
      *(uint4*)&Bs[r * LDS_K + lc * 8] = v;
    }
    __syncthreads();

    #pragma unroll
    for (int s = 0; s < 2; ++s) {
      bf16x8 a[4], b[4];
      #pragma unroll
      for (int i = 0; i < 4; ++i)
        a[i] = *(const bf16x8*)&As[(wm * 64 + i * 16 + frow) * LDS_K + s * 32 + fk];
      #pragma unroll
      for (int j = 0; j < 4; ++j)
        b[j] = *(const bf16x8*)&Bs[(wn * 64 + j * 16 + frow) * LDS_K + s * 32 + fk];
      #pragma unroll
      for (int i = 0; i < 4; ++i)
        #pragma unroll
        for (int j = 0; j < 4; ++j)
          acc[i][j] = __builtin_amdgcn_mfma_f32_16x16x32_bf16(a[i], b[j], acc[i][j], 0, 0, 0);
    }
    __syncthreads();
  }

  #pragma unroll
  for (int i = 0; i < 4; ++i) {
    #pragma unroll
    for (int j = 0; j < 4; ++j) {
      const int col = col0 + wn * 64 + j * 16 + (lane & 15);
      const float bias = b1[col];
      #pragma unroll
      for (int r = 0; r < 4; ++r) {
        const int grow = row0 + wm * 64 + i * 16 + (lane >> 4) * 4 + r;
        if (grow < M) {
          const float v = fmaxf(acc[i][j][r] + bias, 0.f);
          Hb[(size_t)grow * DIM + col] = f2bf(v);
        }
      }
    }
  }
}

// ---------------------------------------------------------------------------
// proj2 via MFMA: Y4v[i][c] = h_i @ W2b[c,:], c in {l0,l1,r0,r1}.
// One wave per 16 nodes; A-frag straight from global H, B-frag from W2b.
// ---------------------------------------------------------------------------
__global__ __launch_bounds__(256) void proj2_mfma(
    const ushort* __restrict__ Hb, const ushort* __restrict__ W2b,
    float* __restrict__ Y4v, int M) {
  const int lane = threadIdx.x & 63;
  const int wave = threadIdx.x >> 6;
  const int row0 = (blockIdx.x * 4 + wave) * 16;
  if (row0 >= M) return;
  const int frow = lane & 15;
  const int fk   = (lane >> 4) * 8;

  f32x4 acc = {};
  #pragma unroll
  for (int s = 0; s < 8; ++s) {
    bf16x8 a = {};
    if (row0 + frow < M)
      a = *(const bf16x8*)(Hb + (size_t)(row0 + frow) * DIM + s * 32 + fk);
    const bf16x8 b = *(const bf16x8*)(W2b + frow * DIM + s * 32 + fk);
    acc = __builtin_amdgcn_mfma_f32_16x16x32_bf16(a, b, acc, 0, 0, 0);
  }
  const int col = lane & 15;
  if (col < 4) {
    #pragma unroll
    for (int r = 0; r < 4; ++r) {
      const int row = row0 + (lane >> 4) * 4 + r;
      if (row < M) Y4v[(size_t)row * 4 + col] = acc[r];
    }
  }
}

// ---------------------------------------------------------------------------
// Layer-2 aggregation + bias + log_softmax, one thread per node via CSR.
// ---------------------------------------------------------------------------
__global__ __launch_bounds__(256) void layer2_finalize(
    const float2* __restrict__ Y2, const int* __restrict__ esrc,
    const int* __restrict__ rowptr, const float* __restrict__ invc,
    const float* __restrict__ b2, float* __restrict__ out, int M) {
  int i = blockIdx.x * blockDim.x + threadIdx.x;
  if (i < M) {
    const int k0 = rowptr[i];
    const int k1 = rowptr[i + 1];
    float a0 = 0.f, a1 = 0.f;
    for (int k = k0; k < k1; ++k) {
      const float2 y = Y2[2 * (size_t)esrc[k]];
      a0 += y.x; a1 += y.y;
    }
    const float inv = invc[i];
    const float2 yr = Y2[2 * (size_t)i + 1];
    const float o0 = a0 * inv + yr.x + b2[0];
    const float o1 = a1 * inv + yr.y + b2[1];
    const float m = fmaxf(o0, o1);
    const float lse = m + logf(expf(o0 - m) + expf(o1 - m));
    out[2 * i + 0] = o0 - lse;
    out[2 * i + 1] = o1 - lse;
  }
}

extern "C" void kernel_launch(void* const* d_in, const int* in_sizes, int n_in,
                              void* d_out, int out_size, void* d_ws, size_t ws_size,
                              hipStream_t stream) {
  const float* x   = (const float*)d_in[0];
  const int*   ei  = (const int*)d_in[1];
  const float* W1l = (const float*)d_in[2];
  const float* b1  = (const float*)d_in[3];
  const float* W1r = (const float*)d_in[4];
  const float* W2l = (const float*)d_in[5];
  const float* b2  = (const float*)d_in[6];
  const float* W2r = (const float*)d_in[7];

  const int E = in_sizes[1] / 2;
  const int M = in_sizes[0] / DIM;  // 50000
  const int* src = ei;
  const int* dst = ei + E;

  char* ws = (char*)d_ws;
  size_t off = 0;
  ushort* xb   = (ushort*)(ws + off); off += (size_t)M * DIM * 2;
  ushort* aggb = (ushort*)(ws + off); off += (size_t)M * DIM * 2;
  ushort* Hb   = (ushort*)(ws + off); off += (size_t)M * DIM * 2;
  ushort* Wb   = (ushort*)(ws + off); off += (size_t)256 * 512 * 2;
  ushort* W2b  = (ushort*)(ws + off); off += (size_t)16 * 256 * 2;
  float* Y4v   = (float*)(ws + off);  off += (size_t)M * 4 * 4;
  float* invc  = (float*)(ws + off);  off += (size_t)M * 4;
  int* deg     = (int*)(ws + off);    off += (size_t)M * 4;
  int* fill    = (int*)(ws + off);    off += (size_t)M * 4;
  int* rowptr  = (int*)(ws + off);    off += (size_t)(M + 1) * 4;
  int* bsum    = (int*)(ws + off);    off += 1024 * 4;
  int* esrc    = (int*)(ws + off);    off += (size_t)E * 4;

  hipMemsetAsync(deg, 0, (size_t)M * 4, stream);

  const int EB = (E + 255) / 256;
  const int NB = (M + SCHUNK - 1) / SCHUNK;  // scan blocks (49)

  convert_x<<<1024, 256, 0, stream>>>((const float4*)x, xb, M * DIM / 4);
  wcat_kernel<<<528, 256, 0, stream>>>(W1l, W1r, W2l, W2r, Wb, W2b);
  hist_kernel<<<EB, 256, 0, stream>>>(dst, deg, E);
  scan_partial<<<NB, 256, 0, stream>>>(deg, bsum, M);
  scan_sums<<<1, 1024, 0, stream>>>(bsum, NB);
  scan_finalize<<<NB, 256, 0, stream>>>(deg, bsum, rowptr, fill, invc, M);
  scatter_edges<<<EB, 256, 0, stream>>>(src, dst, fill, esrc, E);
  gather1<<<(M + 3) / 4, 256, 0, stream>>>(xb, esrc, rowptr, invc, aggb, M);

  dim3 g1((M + GBM - 1) / GBM, DIM / GBN);
  gemm1_mfma<<<g1, 256, 0, stream>>>(aggb, xb, Wb, b1, Hb, M);

  proj2_mfma<<<(M / 16 + 3) / 4 + 1, 256, 0, stream>>>(Hb, W2b, Y4v, M);
  layer2_finalize<<<(M + 255) / 256, 256, 0, stream>>>(
      (const float2*)Y4v, esrc, rowptr, invc, b2, (float*)d_out, M);
}